// Round 8
// baseline (175.103 us; speedup 1.0000x reference)
//
#include <hip/hip_runtime.h>

#define B_SZ 8
#define T_SZ 4096
#define D_SZ 1024
#define N_SZ 128
#define M_SZ (B_SZ*T_SZ)            // 32768
#define C1 32                       // gemm1 tile rows = small scan chunk
#define NC1 (T_SZ/C1)               // 128 small chunks per batch
#define C2 64                       // gemm2 tile rows
#define NC2 (T_SZ/C2)               // 64 big chunks per batch

typedef __attribute__((ext_vector_type(8))) __bf16 bf16x8;
typedef __attribute__((ext_vector_type(4))) float f32x4;
typedef __attribute__((ext_vector_type(4))) unsigned int u32x4;
typedef __attribute__((ext_vector_type(4))) float fvec4;

static __device__ __forceinline__ unsigned short f2bf(float f){
  union { float f; unsigned int u; } v; v.f = f;
  unsigned int r = v.u + 0x7fffu + ((v.u >> 16) & 1u);
  return (unsigned short)(r >> 16);
}

static __device__ __forceinline__ float bf2f(unsigned short s){
  union { unsigned int u; float f; } v; v.u = ((unsigned)s) << 16;
  return v.f;
}

static __device__ __forceinline__ void cp16(const void* g, void* l){
  __builtin_amdgcn_global_load_lds(
      (const __attribute__((address_space(1))) void*)g,
      (__attribute__((address_space(3))) void*)l, 16, 0, 0);
}

static __device__ __forceinline__ f32x4 zero4(){
  f32x4 v = {0.f, 0.f, 0.f, 0.f};
  return v;
}

static __device__ __forceinline__ bf16x8 pack8(fvec4 a, fvec4 b){
  bf16x8 v;
  v[0]=(__bf16)a.x; v[1]=(__bf16)a.y; v[2]=(__bf16)a.z; v[3]=(__bf16)a.w;
  v[4]=(__bf16)b.x; v[5]=(__bf16)b.y; v[6]=(__bf16)b.z; v[7]=(__bf16)b.w;
  return v;
}

// ---------------------------------------------------------------------------
// K0: convert weights to bf16, pre-swizzled.
// bw: [16 kchunks][128 n][64 k]; byte = c*16384 + n*128 + ((kk*2)^((n&7)<<4))
// cw: [8 dchunks][128 d][128 k]; byte = c*32768 + dd*256 + ((k*2)^((dd&15)<<4))
// ---------------------------------------------------------------------------
__global__ __launch_bounds__(256) void k_conv(const float* __restrict__ Bw,
                                              const float* __restrict__ Cw,
                                              unsigned short* __restrict__ bw,
                                              unsigned short* __restrict__ cw){
  int t = blockIdx.x*256 + threadIdx.x;   // 131072 threads total
  {
    int n = t >> 10, k = t & 1023;
    int c = k >> 6, kk = k & 63;
    unsigned byte = (unsigned)c*16384u + (unsigned)n*128u
                  + (unsigned)((kk*2) ^ ((n&7)<<4));
    bw[byte>>1] = f2bf(Bw[n*1024 + k]);
  }
  {
    int d = t >> 7, k = t & 127;
    int c = d >> 7, dd = d & 127;
    unsigned byte = (unsigned)c*32768u + (unsigned)dd*256u
                  + (unsigned)((k*2) ^ ((dd&15)<<4));
    cw[byte>>1] = f2bf(Cw[d*128 + k]);
  }
}

// ---------------------------------------------------------------------------
// GEMM1 (BM=32, grid 1024 -> 4 blocks/CU resident) + 32-row scan carry.
//   Bu[m][n] = (sum_k u[m][k]*B_w[n][k] + B_b[n]) * dt[n]  -> bf16 global
//   carry[chunk32][n] = local scan of the 32-row chunk from h=0 (fp32)
// ---------------------------------------------------------------------------
__global__ __launch_bounds__(256, 4) void k_gemm1c(const float* __restrict__ u,
                                                   const unsigned short* __restrict__ bw,
                                                   const float* __restrict__ Bb,
                                                   const float* __restrict__ logA,
                                                   const float* __restrict__ logdt,
                                                   unsigned short* __restrict__ Bu_bf,
                                                   float* __restrict__ carry){
  __shared__ __align__(16) char smem[20480];
  unsigned short* lA = (unsigned short*)smem;           //  4 KB phase A
  unsigned short* lB = (unsigned short*)(smem + 4096);  // 16 KB phase A
  float*          BuT = (float*)smem;                   // 16 KB after GEMM
  const int tid  = threadIdx.x;
  const int lane = tid & 63;
  const int wave = tid >> 6;
  const int bc   = blockIdx.x;      // 32-row chunk id, 0..1023
  const int m0   = bc * 32;
  const int l15  = lane & 15;
  const int lhi  = lane >> 4;
  const int rt   = (wave & 1) * 16; // row tile of this wave
  const int ct0  = (wave >> 1) * 4; // col tile base of this wave

  f32x4 acc[4];
  #pragma unroll
  for (int i=0;i<4;++i) acc[i] = zero4();

  for (int kc=0; kc<16; ++kc){
    // stage B_w k-chunk: 16KB pre-swizzled via global_load_lds
    #pragma unroll
    for (int rep=0; rep<4; ++rep){
      const char* g = (const char*)bw + kc*16384 + rep*4096 + tid*16;
      cp16(g, (char*)lB + rep*4096 + tid*16);
    }
    // stage u tile (32x64 fp32 -> bf16 swizzled): 1 rep, 8 floats/thread
    {
      int row = tid >> 3, ks = tid & 7;
      const float* src = u + (size_t)(m0+row)*1024 + kc*64 + ks*8;
      fvec4 f0 = *(const fvec4*)src;
      fvec4 f1 = *(const fvec4*)(src+4);
      unsigned byte = (unsigned)row*128u + (unsigned)((ks*16) ^ ((row&7)<<4));
      *(bf16x8*)((char*)lA + byte) = pack8(f0, f1);
    }
    __syncthreads();
    #pragma unroll
    for (int k0=0; k0<64; k0+=32){
      int arow = rt + l15;
      int ak = k0 + lhi*8;
      bf16x8 af = *(const bf16x8*)((const char*)lA + arow*128 + ((ak*2) ^ ((arow&7)<<4)));
      #pragma unroll
      for (int j=0;j<4;++j){
        int bn = (ct0+j)*16 + l15;
        bf16x8 bfv = *(const bf16x8*)((const char*)lB + bn*128 + ((ak*2) ^ ((bn&7)<<4)));
        acc[j] = __builtin_amdgcn_mfma_f32_16x16x32_bf16(af, bfv, acc[j], 0, 0, 0);
      }
    }
    __syncthreads();
  }

  // epilogue: (acc + B_b)*dt -> BuT fp32 (overlays lA/lB after barrier)
  #pragma unroll
  for (int j=0;j<4;++j){
    int n = (ct0+j)*16 + l15;
    float dt = fminf(__expf(logdt[n]), 1.f);
    float bb = Bb[n];
    #pragma unroll
    for (int r=0;r<4;++r){
      int ml = rt + lhi*4 + r;
      BuT[ml*128 + n] = (acc[j][r] + bb) * dt;
    }
  }
  __syncthreads();

  // pack Bu tile to bf16, coalesced 16B stores (512 items of 8 elems)
  #pragma unroll
  for (int i=0;i<2;++i){
    int q = i*256 + tid;
    const float* s = BuT + q*8;
    fvec4 a = *(const fvec4*)s;
    fvec4 b = *(const fvec4*)(s+4);
    u32x4 p;
    p.x = (unsigned)f2bf(a.x) | ((unsigned)f2bf(a.y)<<16);
    p.y = (unsigned)f2bf(a.z) | ((unsigned)f2bf(a.w)<<16);
    p.z = (unsigned)f2bf(b.x) | ((unsigned)f2bf(b.y)<<16);
    p.w = (unsigned)f2bf(b.z) | ((unsigned)f2bf(b.w)<<16);
    *(u32x4*)((char*)Bu_bf + (size_t)bc*8192 + (size_t)q*16) = p;
  }

  // 32-row scan carry (h starts at 0)
  if (tid < 128){
    int n = tid;
    float dt = fminf(__expf(logdt[n]), 1.f);
    float Ab = __expf(-__expf(logA[n]) * dt);
    float h = 0.f;
    #pragma unroll 8
    for (int j=0;j<C1;++j) h = fmaf(Ab, h, BuT[j*128 + n]);
    carry[(size_t)bc*128 + n] = h;
  }
}

// ---------------------------------------------------------------------------
// GEMM2 + prefix + scan. Grid 1024: block = (64-row chunk bc, d-half dh).
// LDS only 32 KB (BuT bf16 + hsT) -> 4 blocks/CU resident, 16 waves/CU.
// cw B-fragments are read DIRECTLY from L2 (cw is 256 KB, L2-resident);
// waves split output by d-columns so cw reads are disjoint across waves.
// The d-loop has NO barriers: after hsT is built, waves free-run.
// ---------------------------------------------------------------------------
__global__ __launch_bounds__(256, 4) void k_gemm2s(
                                                const unsigned short* __restrict__ Bu_bf,
                                                const float* __restrict__ carry,
                                                const unsigned short* __restrict__ cw,
                                                const float* __restrict__ u,
                                                const float* __restrict__ h0,
                                                const float* __restrict__ Cb,
                                                const float* __restrict__ Dp,
                                                const float* __restrict__ logA,
                                                const float* __restrict__ logdt,
                                                float* __restrict__ y){
  __shared__ __align__(16) unsigned short BuT[64*128];      // 16 KB bf16 linear
  __shared__ __align__(16) unsigned short hsT[64*128];      // 16 KB swizzled
  const int tid = threadIdx.x, lane = tid & 63, wave = tid >> 6;
  const int bid = blockIdx.x;
  const int bc  = bid >> 1;          // 64-row chunk, 0..511
  const int dh  = bid & 1;           // d-half: chunks dh*4 .. dh*4+3
  const int m0  = bc * 64;
  const int l15 = lane & 15, lhi = lane >> 4;

  // stage Bu tile (16 KB, 4 rounds) via global_load_lds
  #pragma unroll
  for (int i=0;i<4;++i){
    int off = i*4096 + tid*16;
    cp16((const char*)Bu_bf + (size_t)bc*16384 + off, (char*)BuT + off);
  }

  // cross-chunk prefix over 32-row carries (batched, group-skipped)
  float hreg = 0.f, Ab = 0.f;
  if (tid < 128){
    int n = tid;
    int b = bc >> 6;
    int c32 = (bc & 63) * 2;         // # of 32-row chunks before this tile
    float dt = fminf(__expf(logdt[n]), 1.f);
    float Ad = -__expf(logA[n]) * dt;
    Ab = __expf(Ad);
    float AL = __expf(Ad * (float)C1);
    float h = h0[b*128 + n];
    const float* cp = carry + (size_t)b*NC1*128 + n;
    for (int g=0; g<8; ++g){
      if (g*16 >= c32) break;        // block-uniform skip
      float cbuf[16];
      #pragma unroll
      for (int i=0;i<16;++i) cbuf[i] = cp[(size_t)(g*16+i)*128];
      #pragma unroll
      for (int i=0;i<16;++i){
        int idx = g*16 + i;
        h = (idx < c32) ? fmaf(AL, h, cbuf[i]) : h;
      }
    }
    hreg = h;
  }
  __syncthreads();     // BuT staged

  // 64-step local scan -> swizzled bf16 hsT
  if (tid < 128){
    int n = tid;
    float h = hreg;
    #pragma unroll 8
    for (int j=0;j<C2;++j){
      h = fmaf(Ab, h, bf2f(BuT[j*128 + n]));
      unsigned byte = (unsigned)j*256u + (unsigned)((n*2) ^ ((j&15)<<4));
      *(unsigned short*)((char*)hsT + byte) = f2bf(h);
    }
  }
  __syncthreads();     // hsT ready; waves free-run from here (no more barriers)

  for (int dc4=0; dc4<4; ++dc4){
    const int d = dh*4 + dc4;
    const char* cwd = (const char*)cw + (size_t)d*32768;

    f32x4 acc[4][2];
    #pragma unroll
    for (int i=0;i<4;++i)
      #pragma unroll
      for (int j=0;j<2;++j) acc[i][j] = zero4();

    #pragma unroll
    for (int k0=0;k0<128;k0+=32){
      int ak = k0 + lhi*8;
      bf16x8 af[4];
      #pragma unroll
      for (int mt=0;mt<4;++mt){
        int arow = mt*16 + l15;
        af[mt] = *(const bf16x8*)((const char*)hsT + arow*256 + ((ak*2) ^ ((arow&15)<<4)));
      }
      #pragma unroll
      for (int dt=0;dt<2;++dt){
        int dn = (wave*2 + dt)*16 + l15;
        bf16x8 bfv = *(const bf16x8*)(cwd + dn*256 + ((ak*2) ^ ((dn&15)<<4)));
        #pragma unroll
        for (int mt=0;mt<4;++mt)
          acc[mt][dt] = __builtin_amdgcn_mfma_f32_16x16x32_bf16(af[mt], bfv,
                                                                acc[mt][dt], 0, 0, 0);
      }
    }

    // epilogue: y = acc + Cb + Dp*u
    const int d0 = d*128;
    #pragma unroll
    for (int dt=0;dt<2;++dt){
      int dcol = d0 + (wave*2 + dt)*16 + l15;
      float cb = Cb[dcol], dp = Dp[dcol];
      #pragma unroll
      for (int mt=0;mt<4;++mt){
        #pragma unroll
        for (int r=0;r<4;++r){
          int m = m0 + mt*16 + lhi*4 + r;
          size_t off = (size_t)m*1024 + dcol;
          y[off] = acc[mt][dt][r] + cb + dp*u[off];
        }
      }
    }
  }
}

// ---------------------------------------------------------------------------
extern "C" void kernel_launch(void* const* d_in, const int* in_sizes, int n_in,
                              void* d_out, int out_size, void* d_ws, size_t ws_size,
                              hipStream_t stream){
  (void)in_sizes; (void)n_in; (void)out_size; (void)ws_size;
  const float* u     = (const float*)d_in[0];
  const float* h0    = (const float*)d_in[1];
  const float* logA  = (const float*)d_in[2];
  const float* Bw    = (const float*)d_in[3];
  const float* Bb    = (const float*)d_in[4];
  const float* Cw    = (const float*)d_in[5];
  const float* Cb    = (const float*)d_in[6];
  const float* Dp    = (const float*)d_in[7];
  const float* logdt = (const float*)d_in[8];
  float* y = (float*)d_out;

  char* ws = (char*)d_ws;
  unsigned short* Bu_bf = (unsigned short*)(ws);             // 8,388,608 B
  float*          carry = (float*)(ws + 8388608);            //   524,288 B
  unsigned short* bw    = (unsigned short*)(ws + 8912896);   //   262,144 B
  unsigned short* cw    = (unsigned short*)(ws + 9175040);   //   262,144 B
  // total ws use: 9,437,184 B

  k_conv  <<<dim3(512),  dim3(256), 0, stream>>>(Bw, Cw, bw, cw);
  k_gemm1c<<<dim3(1024), dim3(256), 0, stream>>>(u, bw, Bb, logA, logdt, Bu_bf, carry);
  k_gemm2s<<<dim3(1024), dim3(256), 0, stream>>>(Bu_bf, carry, cw, u, h0, Cb, Dp,
                                                 logA, logdt, y);
}

// Round 9
// 90.381 us; speedup vs baseline: 1.9374x; 1.9374x over previous
//
#include <hip/hip_runtime.h>

#define B_SZ 8
#define T_SZ 4096
#define D_SZ 1024
#define N_SZ 128
#define M_SZ (B_SZ*T_SZ)          // 32768
#define CHUNK 64                  // scan chunk length = GEMM tile rows
#define NCHUNK (T_SZ/CHUNK)       // 64 chunks per batch

typedef __attribute__((ext_vector_type(8))) __bf16 bf16x8;
typedef __attribute__((ext_vector_type(4))) float f32x4;
typedef __attribute__((ext_vector_type(4))) unsigned int u32x4;
typedef __attribute__((ext_vector_type(4))) float fvec4;

static __device__ __forceinline__ unsigned short f2bf(float f){
  union { float f; unsigned int u; } v; v.f = f;
  unsigned int r = v.u + 0x7fffu + ((v.u >> 16) & 1u);
  return (unsigned short)(r >> 16);
}

static __device__ __forceinline__ float bf2f(unsigned short s){
  union { unsigned int u; float f; } v; v.u = ((unsigned)s) << 16;
  return v.f;
}

static __device__ __forceinline__ void cp16(const void* g, void* l){
  __builtin_amdgcn_global_load_lds(
      (const __attribute__((address_space(1))) void*)g,
      (__attribute__((address_space(3))) void*)l, 16, 0, 0);
}

static __device__ __forceinline__ f32x4 zero4(){
  f32x4 v = {0.f, 0.f, 0.f, 0.f};
  return v;
}

// ---------------------------------------------------------------------------
// K0: convert weights to bf16, pre-swizzled so GEMM tiles are contiguous
// global_load_lds images.
// bw: [16 kchunks][128 n][64 k] bf16; byte = c*16384 + n*128 + ((kk*2)^((n&7)<<4))
// cw: [8 dchunks][128 d][128 k] bf16; byte = c*32768 + dd*256 + ((k*2)^((dd&15)<<4))
// ---------------------------------------------------------------------------
__global__ __launch_bounds__(256) void k_conv(const float* __restrict__ Bw,
                                              const float* __restrict__ Cw,
                                              unsigned short* __restrict__ bw,
                                              unsigned short* __restrict__ cw){
  int t = blockIdx.x*256 + threadIdx.x;   // 131072 threads total
  {
    int n = t >> 10, k = t & 1023;
    int c = k >> 6, kk = k & 63;
    unsigned byte = (unsigned)c*16384u + (unsigned)n*128u
                  + (unsigned)((kk*2) ^ ((n&7)<<4));
    bw[byte>>1] = f2bf(Bw[n*1024 + k]);
  }
  {
    int d = t >> 7, k = t & 127;
    int c = d >> 7, dd = d & 127;
    unsigned byte = (unsigned)c*32768u + (unsigned)dd*256u
                  + (unsigned)((k*2) ^ ((dd&15)<<4));
    cw[byte>>1] = f2bf(Cw[d*128 + k]);
  }
}

// ---------------------------------------------------------------------------
// GEMM1 + chunk-local scan carry (fused) — identical to the 87.9 µs R4 best.
//   Bu[m][n] = (sum_k u[m][k]*B_w[n][k] + B_b[n]) * dt[n]  -> bf16 to global
//   carry[chunk][n] = local scan of the 64-row chunk starting from h=0 (fp32)
// ---------------------------------------------------------------------------
__global__ __launch_bounds__(256) void k_gemm1c(const float* __restrict__ u,
                                                const unsigned short* __restrict__ bw,
                                                const float* __restrict__ Bb,
                                                const float* __restrict__ logA,
                                                const float* __restrict__ logdt,
                                                unsigned short* __restrict__ Bu_bf,
                                                float* __restrict__ carry){
  __shared__ __align__(16) char smem[32768];
  unsigned short* lA = (unsigned short*)smem;           //  8 KB during GEMM
  unsigned short* lB = (unsigned short*)(smem + 8192);  // 16 KB during GEMM
  float*          BuT = (float*)smem;                   // 32 KB after GEMM
  const int tid  = threadIdx.x;
  const int lane = tid & 63;
  const int wave = tid >> 6;
  const int bc   = blockIdx.x;
  const int m0   = bc * 64;
  const int l15  = lane & 15;
  const int lhi  = lane >> 4;

  f32x4 acc[8];
  #pragma unroll
  for (int i=0;i<8;++i) acc[i] = zero4();

  for (int kc=0; kc<16; ++kc){
    #pragma unroll
    for (int rep=0; rep<4; ++rep){
      const char* g = (const char*)bw + kc*16384 + rep*4096 + wave*1024 + lane*16;
      char* l = (char*)lB + rep*4096 + wave*1024;
      cp16(g, l);
    }
    #pragma unroll
    for (int rep=0; rep<2; ++rep){
      int q = rep*256 + tid;            // 0..511
      int row = q >> 3, ks = q & 7;
      const float* src = u + (size_t)(m0+row)*1024 + kc*64 + ks*8;
      fvec4 f0 = *(const fvec4*)src;
      fvec4 f1 = *(const fvec4*)(src+4);
      u32x4 p;
      p.x = (unsigned)f2bf(f0.x) | ((unsigned)f2bf(f0.y)<<16);
      p.y = (unsigned)f2bf(f0.z) | ((unsigned)f2bf(f0.w)<<16);
      p.z = (unsigned)f2bf(f1.x) | ((unsigned)f2bf(f1.y)<<16);
      p.w = (unsigned)f2bf(f1.z) | ((unsigned)f2bf(f1.w)<<16);
      unsigned byte = (unsigned)row*128u + (unsigned)((ks*16) ^ ((row&7)<<4));
      *(u32x4*)((char*)lA + byte) = p;
    }
    __syncthreads();
    #pragma unroll
    for (int k0=0; k0<64; k0+=32){
      int arow = wave*16 + l15;
      int ak = k0 + lhi*8;
      bf16x8 af = *(const bf16x8*)((const char*)lA + arow*128 + ((ak*2) ^ ((arow&7)<<4)));
      #pragma unroll
      for (int ct=0; ct<8; ++ct){
        int bn = ct*16 + l15;
        bf16x8 bfv = *(const bf16x8*)((const char*)lB + bn*128 + ((ak*2) ^ ((bn&7)<<4)));
        acc[ct] = __builtin_amdgcn_mfma_f32_16x16x32_bf16(af, bfv, acc[ct], 0, 0, 0);
      }
    }
    __syncthreads();
  }

  #pragma unroll
  for (int ct=0; ct<8; ++ct){
    int n = ct*16 + l15;
    float dt = fminf(__expf(logdt[n]), 1.f);
    float bb = Bb[n];
    #pragma unroll
    for (int r=0;r<4;++r){
      int ml = wave*16 + lhi*4 + r;
      BuT[ml*128 + n] = (acc[ct][r] + bb) * dt;
    }
  }
  __syncthreads();

  #pragma unroll
  for (int i=0;i<4;++i){
    int q = i*256 + tid;
    const float* s = BuT + q*8;
    fvec4 a = *(const fvec4*)s;
    fvec4 b = *(const fvec4*)(s+4);
    u32x4 p;
    p.x = (unsigned)f2bf(a.x) | ((unsigned)f2bf(a.y)<<16);
    p.y = (unsigned)f2bf(a.z) | ((unsigned)f2bf(a.w)<<16);
    p.z = (unsigned)f2bf(b.x) | ((unsigned)f2bf(b.y)<<16);
    p.w = (unsigned)f2bf(b.z) | ((unsigned)f2bf(b.w)<<16);
    *(u32x4*)((char*)Bu_bf + (size_t)bc*16384 + (size_t)q*16) = p;
  }

  if (tid < 128){
    int n = tid;
    float dt = fminf(__expf(logdt[n]), 1.f);
    float Ab = __expf(-__expf(logA[n]) * dt);
    float h = 0.f;
    #pragma unroll 8
    for (int j=0;j<CHUNK;++j) h = fmaf(Ab, h, BuT[j*128 + n]);
    carry[(size_t)bc*128 + n] = h;
  }
}

// ---------------------------------------------------------------------------
// GEMM2 + prefix + scan. Grid 1024: block = (64-row chunk bc, d-half dh).
// hs A-fragments hoisted to registers (16 VGPR/wave) after the scan, so cwT
// overlays the hsT/BuT region: LDS = 32 KB -> 4 blocks/CU resident.
// MFMA layout + epilogue addressing identical to the validated R4 kernel.
// ---------------------------------------------------------------------------
__global__ __launch_bounds__(256, 4) void k_gemm2s(
                                                const unsigned short* __restrict__ Bu_bf,
                                                const float* __restrict__ carry,
                                                const unsigned short* __restrict__ cw,
                                                const float* __restrict__ u,
                                                const float* __restrict__ h0,
                                                const float* __restrict__ Cb,
                                                const float* __restrict__ Dp,
                                                const float* __restrict__ logA,
                                                const float* __restrict__ logdt,
                                                float* __restrict__ y){
  __shared__ __align__(16) char smem[32768];
  unsigned short* BuT = (unsigned short*)smem;            // 16 KB (phase 1)
  unsigned short* hsT = (unsigned short*)(smem + 16384);  // 16 KB (phase 1)
  unsigned short* cwT = (unsigned short*)smem;            // 32 KB (phase 2)
  const int tid = threadIdx.x, lane = tid & 63, wave = tid >> 6;
  const int bid = blockIdx.x;
  const int bc  = bid >> 1;          // 64-row chunk, 0..511
  const int dh  = bid & 1;           // d-half: chunks dh*4 .. dh*4+3
  const int m0  = bc * 64;
  const int l15 = lane & 15, lhi = lane >> 4;

  // stage Bu tile (16 KB, 4 rounds) via global_load_lds (drained at barrier)
  #pragma unroll
  for (int i=0;i<4;++i){
    int off = i*4096 + tid*16;
    cp16((const char*)Bu_bf + (size_t)bc*16384 + off, (char*)BuT + off);
  }

  // cross-chunk prefix in registers (overlaps with the staging above)
  float hreg = 0.f, Ab = 0.f;
  if (tid < 128){
    int n = tid;
    int b = bc >> 6, c = bc & 63;
    float dt = fminf(__expf(logdt[n]), 1.f);
    float Ad = -__expf(logA[n]) * dt;
    Ab = __expf(Ad);
    float AL = __expf(Ad * (float)CHUNK);
    float h = h0[b*128 + n];
    const float* cp = carry + (size_t)b*NCHUNK*128 + n;
    #pragma unroll
    for (int g=0; g<4; ++g){
      float cbuf[16];
      #pragma unroll
      for (int i=0;i<16;++i) cbuf[i] = cp[(size_t)(g*16+i)*128];
      #pragma unroll
      for (int i=0;i<16;++i){
        int idx = g*16 + i;
        h = (idx < c) ? fmaf(AL, h, cbuf[i]) : h;
      }
    }
    hreg = h;
  }
  __syncthreads();     // BuT staged

  // 64-step local scan -> swizzled bf16 hsT
  if (tid < 128){
    int n = tid;
    float h = hreg;
    #pragma unroll 8
    for (int j=0;j<CHUNK;++j){
      h = fmaf(Ab, h, bf2f(BuT[j*128 + n]));
      unsigned byte = (unsigned)j*256u + (unsigned)((n*2) ^ ((j&15)<<4));
      *(unsigned short*)((char*)hsT + byte) = f2bf(h);
    }
  }
  __syncthreads();     // hsT complete

  // hoist this wave's hs A-fragments into registers (4 x bf16x8 = 16 VGPR)
  bf16x8 afr[4];
  {
    int arow = wave*16 + l15;
    #pragma unroll
    for (int k0i=0;k0i<4;++k0i){
      int ak = k0i*32 + lhi*8;
      afr[k0i] = *(const bf16x8*)((const char*)hsT + arow*256 + ((ak*2) ^ ((arow&15)<<4)));
    }
  }
  __syncthreads();     // all waves done with hsT; cwT may overlay it

  // stage first cw chunk of this d-half (32 KB, 8 rounds)
  #pragma unroll
  for (int i=0;i<8;++i){
    int off = i*4096 + tid*16;
    cp16((const char*)cw + (size_t)(dh*4)*32768 + off, (char*)cwT + off);
  }

  for (int dc4=0; dc4<4; ++dc4){
    const int d = dh*4 + dc4;
    __syncthreads();            // cwT staged (drains cp16)

    f32x4 acc[8];
    #pragma unroll
    for (int i=0;i<8;++i) acc[i] = zero4();

    #pragma unroll
    for (int k0i=0;k0i<4;++k0i){
      int ak = k0i*32 + lhi*8;
      #pragma unroll
      for (int ct=0;ct<8;++ct){
        int bn = ct*16 + l15;
        bf16x8 bfv = *(const bf16x8*)((const char*)cwT + bn*256 + ((ak*2) ^ ((bn&15)<<4)));
        acc[ct] = __builtin_amdgcn_mfma_f32_16x16x32_bf16(afr[k0i], bfv, acc[ct], 0, 0, 0);
      }
    }
    __syncthreads();            // all waves done reading cwT

    if (dc4 < 3){               // stage next cw chunk (async, hides under epilogue)
      #pragma unroll
      for (int i=0;i<8;++i){
        int off = (wave*8 + i)*1024 + lane*16;
        cp16((const char*)cw + (size_t)(d+1)*32768 + off, (char*)cwT + off);
      }
    }

    // epilogue: y = acc + Cb + Dp*u (same coalescing-correct layout as R4)
    const int d0 = d*128;
    #pragma unroll
    for (int ct=0;ct<8;++ct){
      int dc = d0 + ct*16 + l15;
      float cb = Cb[dc], dp = Dp[dc];
      #pragma unroll
      for (int r=0;r<4;++r){
        int m = m0 + wave*16 + lhi*4 + r;
        size_t off = (size_t)m*1024 + dc;
        y[off] = acc[ct][r] + cb + dp*u[off];
      }
    }
  }
}

// ---------------------------------------------------------------------------
extern "C" void kernel_launch(void* const* d_in, const int* in_sizes, int n_in,
                              void* d_out, int out_size, void* d_ws, size_t ws_size,
                              hipStream_t stream){
  (void)in_sizes; (void)n_in; (void)out_size; (void)ws_size;
  const float* u     = (const float*)d_in[0];
  const float* h0    = (const float*)d_in[1];
  const float* logA  = (const float*)d_in[2];
  const float* Bw    = (const float*)d_in[3];
  const float* Bb    = (const float*)d_in[4];
  const float* Cw    = (const float*)d_in[5];
  const float* Cb    = (const float*)d_in[6];
  const float* Dp    = (const float*)d_in[7];
  const float* logdt = (const float*)d_in[8];
  float* y = (float*)d_out;

  char* ws = (char*)d_ws;
  unsigned short* Bu_bf = (unsigned short*)(ws);             // 8,388,608 B
  float*          carry = (float*)(ws + 8388608);            //   262,144 B
  unsigned short* bw    = (unsigned short*)(ws + 8650752);   //   262,144 B
  unsigned short* cw    = (unsigned short*)(ws + 8912896);   //   262,144 B
  // total ws use: 9,175,040 B

  k_conv  <<<dim3(512),  dim3(256), 0, stream>>>(Bw, Cw, bw, cw);
  k_gemm1c<<<dim3(512),  dim3(256), 0, stream>>>(u, bw, Bb, logA, logdt, Bu_bf, carry);
  k_gemm2s<<<dim3(1024), dim3(256), 0, stream>>>(Bu_bf, carry, cw, u, h0, Cb, Dp,
                                                 logA, logdt, y);
}

// Round 10
// 85.448 us; speedup vs baseline: 2.0492x; 1.0577x over previous
//
#include <hip/hip_runtime.h>

#define B_SZ 8
#define T_SZ 4096
#define D_SZ 1024
#define N_SZ 128
#define M_SZ (B_SZ*T_SZ)            // 32768
#define C1 32                       // gemm1 tile rows = small scan chunk
#define NC1 (T_SZ/C1)               // 128 small chunks per batch
#define C2 64                       // gemm2 tile rows
#define NC2 (T_SZ/C2)               // 64 big chunks per batch

typedef __attribute__((ext_vector_type(8))) __bf16 bf16x8;
typedef __attribute__((ext_vector_type(4))) float f32x4;
typedef __attribute__((ext_vector_type(4))) unsigned int u32x4;
typedef __attribute__((ext_vector_type(4))) float fvec4;

static __device__ __forceinline__ unsigned short f2bf(float f){
  union { float f; unsigned int u; } v; v.f = f;
  unsigned int r = v.u + 0x7fffu + ((v.u >> 16) & 1u);
  return (unsigned short)(r >> 16);
}

static __device__ __forceinline__ float bf2f(unsigned short s){
  union { unsigned int u; float f; } v; v.u = ((unsigned)s) << 16;
  return v.f;
}

static __device__ __forceinline__ void cp16(const void* g, void* l){
  __builtin_amdgcn_global_load_lds(
      (const __attribute__((address_space(1))) void*)g,
      (__attribute__((address_space(3))) void*)l, 16, 0, 0);
}

static __device__ __forceinline__ f32x4 zero4(){
  f32x4 v = {0.f, 0.f, 0.f, 0.f};
  return v;
}

static __device__ __forceinline__ bf16x8 pack8(fvec4 a, fvec4 b){
  bf16x8 v;
  v[0]=(__bf16)a.x; v[1]=(__bf16)a.y; v[2]=(__bf16)a.z; v[3]=(__bf16)a.w;
  v[4]=(__bf16)b.x; v[5]=(__bf16)b.y; v[6]=(__bf16)b.z; v[7]=(__bf16)b.w;
  return v;
}

// ---------------------------------------------------------------------------
// K0: convert weights to bf16, pre-swizzled.
// bw: [16 kchunks][128 n][64 k]; byte = c*16384 + n*128 + ((kk*2)^((n&7)<<4))
// cw: [8 dchunks][128 d][128 k]; byte = c*32768 + dd*256 + ((k*2)^((dd&15)<<4))
// ---------------------------------------------------------------------------
__global__ __launch_bounds__(256) void k_conv(const float* __restrict__ Bw,
                                              const float* __restrict__ Cw,
                                              unsigned short* __restrict__ bw,
                                              unsigned short* __restrict__ cw){
  int t = blockIdx.x*256 + threadIdx.x;   // 131072 threads total
  {
    int n = t >> 10, k = t & 1023;
    int c = k >> 6, kk = k & 63;
    unsigned byte = (unsigned)c*16384u + (unsigned)n*128u
                  + (unsigned)((kk*2) ^ ((n&7)<<4));
    bw[byte>>1] = f2bf(Bw[n*1024 + k]);
  }
  {
    int d = t >> 7, k = t & 127;
    int c = d >> 7, dd = d & 127;
    unsigned byte = (unsigned)c*32768u + (unsigned)dd*256u
                  + (unsigned)((k*2) ^ ((dd&15)<<4));
    cw[byte>>1] = f2bf(Cw[d*128 + k]);
  }
}

// ---------------------------------------------------------------------------
// GEMM1 (BM=32, grid 1024, 4 blocks/CU resident) + 32-row scan carry.
// Proven ~12 us (R8 profile: total - gemm2s = 14.6 us incl. conv).
// ---------------------------------------------------------------------------
__global__ __launch_bounds__(256, 4) void k_gemm1c(const float* __restrict__ u,
                                                   const unsigned short* __restrict__ bw,
                                                   const float* __restrict__ Bb,
                                                   const float* __restrict__ logA,
                                                   const float* __restrict__ logdt,
                                                   unsigned short* __restrict__ Bu_bf,
                                                   float* __restrict__ carry){
  __shared__ __align__(16) char smem[20480];
  unsigned short* lA = (unsigned short*)smem;           //  4 KB phase A
  unsigned short* lB = (unsigned short*)(smem + 4096);  // 16 KB phase A
  float*          BuT = (float*)smem;                   // 16 KB after GEMM
  const int tid  = threadIdx.x;
  const int lane = tid & 63;
  const int wave = tid >> 6;
  const int bc   = blockIdx.x;      // 32-row chunk id, 0..1023
  const int m0   = bc * 32;
  const int l15  = lane & 15;
  const int lhi  = lane >> 4;
  const int rt   = (wave & 1) * 16; // row tile of this wave
  const int ct0  = (wave >> 1) * 4; // col tile base of this wave

  f32x4 acc[4];
  #pragma unroll
  for (int i=0;i<4;++i) acc[i] = zero4();

  for (int kc=0; kc<16; ++kc){
    #pragma unroll
    for (int rep=0; rep<4; ++rep){
      const char* g = (const char*)bw + kc*16384 + rep*4096 + tid*16;
      cp16(g, (char*)lB + rep*4096 + tid*16);
    }
    {
      int row = tid >> 3, ks = tid & 7;
      const float* src = u + (size_t)(m0+row)*1024 + kc*64 + ks*8;
      fvec4 f0 = *(const fvec4*)src;
      fvec4 f1 = *(const fvec4*)(src+4);
      unsigned byte = (unsigned)row*128u + (unsigned)((ks*16) ^ ((row&7)<<4));
      *(bf16x8*)((char*)lA + byte) = pack8(f0, f1);
    }
    __syncthreads();
    #pragma unroll
    for (int k0=0; k0<64; k0+=32){
      int arow = rt + l15;
      int ak = k0 + lhi*8;
      bf16x8 af = *(const bf16x8*)((const char*)lA + arow*128 + ((ak*2) ^ ((arow&7)<<4)));
      #pragma unroll
      for (int j=0;j<4;++j){
        int bn = (ct0+j)*16 + l15;
        bf16x8 bfv = *(const bf16x8*)((const char*)lB + bn*128 + ((ak*2) ^ ((bn&7)<<4)));
        acc[j] = __builtin_amdgcn_mfma_f32_16x16x32_bf16(af, bfv, acc[j], 0, 0, 0);
      }
    }
    __syncthreads();
  }

  // epilogue: (acc + B_b)*dt -> BuT fp32 (overlays lA/lB after barrier)
  #pragma unroll
  for (int j=0;j<4;++j){
    int n = (ct0+j)*16 + l15;
    float dt = fminf(__expf(logdt[n]), 1.f);
    float bb = Bb[n];
    #pragma unroll
    for (int r=0;r<4;++r){
      int ml = rt + lhi*4 + r;
      BuT[ml*128 + n] = (acc[j][r] + bb) * dt;
    }
  }
  __syncthreads();

  // pack Bu tile to bf16, coalesced 16B stores (512 items of 8 elems)
  #pragma unroll
  for (int i=0;i<2;++i){
    int q = i*256 + tid;
    const float* s = BuT + q*8;
    fvec4 a = *(const fvec4*)s;
    fvec4 b = *(const fvec4*)(s+4);
    u32x4 p;
    p.x = (unsigned)f2bf(a.x) | ((unsigned)f2bf(a.y)<<16);
    p.y = (unsigned)f2bf(a.z) | ((unsigned)f2bf(a.w)<<16);
    p.z = (unsigned)f2bf(b.x) | ((unsigned)f2bf(b.y)<<16);
    p.w = (unsigned)f2bf(b.z) | ((unsigned)f2bf(b.w)<<16);
    *(u32x4*)((char*)Bu_bf + (size_t)bc*8192 + (size_t)q*16) = p;
  }

  // 32-row scan carry (h starts at 0)
  if (tid < 128){
    int n = tid;
    float dt = fminf(__expf(logdt[n]), 1.f);
    float Ab = __expf(-__expf(logA[n]) * dt);
    float h = 0.f;
    #pragma unroll 8
    for (int j=0;j<C1;++j) h = fmaf(Ab, h, BuT[j*128 + n]);
    carry[(size_t)bc*128 + n] = h;
  }
}

// ---------------------------------------------------------------------------
// GEMM2 + prefix + scan (R4's 87.9 us champion, verbatim except the prefix
// walks 32-row carries). One block per 64-row m-chunk, grid 512, 64 KB LDS.
// ---------------------------------------------------------------------------
__global__ __launch_bounds__(256) void k_gemm2s(const unsigned short* __restrict__ Bu_bf,
                                                const float* __restrict__ carry,
                                                const unsigned short* __restrict__ cw,
                                                const float* __restrict__ u,
                                                const float* __restrict__ h0,
                                                const float* __restrict__ Cb,
                                                const float* __restrict__ Dp,
                                                const float* __restrict__ logA,
                                                const float* __restrict__ logdt,
                                                float* __restrict__ y){
  __shared__ __align__(16) unsigned short BuT[64*128];      // 16 KB bf16 linear
  __shared__ __align__(16) unsigned short hsT[64*128];      // 16 KB swizzled
  __shared__ __align__(16) unsigned short cwT[128*128];     // 32 KB swizzled
  const int tid = threadIdx.x, lane = tid & 63, wave = tid >> 6;
  const int bc = blockIdx.x;
  const int m0 = bc * 64;
  const int l15 = lane & 15, lhi = lane >> 4;

  // stage Bu tile (4 rounds) + cw chunk 0 (8 rounds); async, drained at barrier
  #pragma unroll
  for (int i=0;i<4;++i){
    int off = i*4096 + tid*16;
    cp16((const char*)Bu_bf + (size_t)bc*16384 + off, (char*)BuT + off);
  }
  #pragma unroll
  for (int i=0;i<8;++i){
    int off = i*4096 + tid*16;
    cp16((const char*)cw + off, (char*)cwT + off);
  }

  // cross-chunk prefix over 32-row carries (batched, block-uniform skip);
  // overlaps with the async staging above.
  float hreg = 0.f, Ab = 0.f;
  if (tid < 128){
    int n = tid;
    int b = bc >> 6;
    int c32 = (bc & 63) * 2;         // # of 32-row chunks before this tile
    float dt = fminf(__expf(logdt[n]), 1.f);
    float Ad = -__expf(logA[n]) * dt;
    Ab = __expf(Ad);
    float AL = __expf(Ad * (float)C1);
    float h = h0[b*128 + n];
    const float* cp = carry + (size_t)b*NC1*128 + n;
    for (int g=0; g<8; ++g){
      if (g*16 >= c32) break;        // block-uniform skip
      float cbuf[16];
      #pragma unroll
      for (int i=0;i<16;++i) cbuf[i] = cp[(size_t)(g*16+i)*128];
      #pragma unroll
      for (int i=0;i<16;++i){
        int idx = g*16 + i;
        h = (idx < c32) ? fmaf(AL, h, cbuf[i]) : h;
      }
    }
    hreg = h;
  }
  __syncthreads();

  // local scan (bf16 Bu from LDS) -> swizzled bf16 hsT
  if (tid < 128){
    int n = tid;
    float h = hreg;
    #pragma unroll 8
    for (int j=0;j<C2;++j){
      h = fmaf(Ab, h, bf2f(BuT[j*128 + n]));
      unsigned byte = (unsigned)j*256u + (unsigned)((n*2) ^ ((j&15)<<4));
      *(unsigned short*)((char*)hsT + byte) = f2bf(h);
    }
  }
  __syncthreads();

  for (int d=0; d<8; ++d){
    f32x4 acc[8];
    #pragma unroll
    for (int i=0;i<8;++i) acc[i] = zero4();

    #pragma unroll
    for (int k0=0;k0<128;k0+=32){
      int arow = wave*16 + l15;
      int ak = k0 + lhi*8;
      bf16x8 af = *(const bf16x8*)((const char*)hsT + arow*256 + ((ak*2) ^ ((arow&15)<<4)));
      #pragma unroll
      for (int ct=0;ct<8;++ct){
        int dn = ct*16 + l15;
        bf16x8 bfv = *(const bf16x8*)((const char*)cwT + dn*256 + ((ak*2) ^ ((dn&15)<<4)));
        acc[ct] = __builtin_amdgcn_mfma_f32_16x16x32_bf16(af, bfv, acc[ct], 0, 0, 0);
      }
    }
    __syncthreads();              // all waves done reading cwT

    if (d < 7){                   // stage next cw chunk (async)
      #pragma unroll
      for (int i=0;i<8;++i){
        int off = (wave*8 + i)*1024 + lane*16;
        cp16((const char*)cw + (size_t)(d+1)*32768 + off, (char*)cwT + off);
      }
    }

    // epilogue: y = acc + Cb + Dp*u  (overlaps the async staging)
    const int d0 = d*128;
    #pragma unroll
    for (int ct=0;ct<8;++ct){
      int dc = d0 + ct*16 + l15;
      float cb = Cb[dc], dp = Dp[dc];
      #pragma unroll
      for (int r=0;r<4;++r){
        int m = m0 + wave*16 + lhi*4 + r;
        size_t off = (size_t)m*1024 + dc;
        y[off] = acc[ct][r] + cb + dp*u[off];
      }
    }
    __syncthreads();              // drains cp16s before next MFMA
  }
}

// ---------------------------------------------------------------------------
extern "C" void kernel_launch(void* const* d_in, const int* in_sizes, int n_in,
                              void* d_out, int out_size, void* d_ws, size_t ws_size,
                              hipStream_t stream){
  (void)in_sizes; (void)n_in; (void)out_size; (void)ws_size;
  const float* u     = (const float*)d_in[0];
  const float* h0    = (const float*)d_in[1];
  const float* logA  = (const float*)d_in[2];
  const float* Bw    = (const float*)d_in[3];
  const float* Bb    = (const float*)d_in[4];
  const float* Cw    = (const float*)d_in[5];
  const float* Cb    = (const float*)d_in[6];
  const float* Dp    = (const float*)d_in[7];
  const float* logdt = (const float*)d_in[8];
  float* y = (float*)d_out;

  char* ws = (char*)d_ws;
  unsigned short* Bu_bf = (unsigned short*)(ws);             // 8,388,608 B
  float*          carry = (float*)(ws + 8388608);            //   524,288 B
  unsigned short* bw    = (unsigned short*)(ws + 8912896);   //   262,144 B
  unsigned short* cw    = (unsigned short*)(ws + 9175040);   //   262,144 B
  // total ws use: 9,437,184 B

  k_conv  <<<dim3(512),  dim3(256), 0, stream>>>(Bw, Cw, bw, cw);
  k_gemm1c<<<dim3(1024), dim3(256), 0, stream>>>(u, bw, Bb, logA, logdt, Bu_bf, carry);
  k_gemm2s<<<dim3(512),  dim3(256), 0, stream>>>(Bu_bf, carry, cw, u, h0, Cb, Dp,
                                                 logA, logdt, y);
}